// Round 12
// baseline (36.397 us; speedup 1.0000x reference)
//
#include <hip/hip_runtime.h>

#define NF       10000
#define NF_PAD   10240
#define PATCH    16
#define ENC      128
#define BB       8
#define HH       64
#define WW       32
#define NPOS     (BB*HH*WW)   // 16384
#define NBUCK    1792
#define BPT      7            // bins per thread in the scan (256*7 = 1792)
#define QPB      32           // queries per K3 block (512 blocks)
#define FSUM_BLOCKS 40
#define XSUM_BLOCKS 64

// f32 sum of 16, shuffle-halving tree order (CONFIRMED ref order, R7-R11).
__device__ __forceinline__ float tree_sum16(const float* a) {
    float b0 = a[0] + a[8],  b1 = a[1] + a[9],  b2 = a[2] + a[10], b3 = a[3] + a[11];
    float b4 = a[4] + a[12], b5 = a[5] + a[13], b6 = a[6] + a[14], b7 = a[7] + a[15];
    float c0 = b0 + b4, c1 = b1 + b5, c2 = b2 + b6, c3 = b3 + b7;
    float d0 = c0 + c2, d1 = c1 + c3;
    return d0 + d1;
}

// ---------------------------------------------------------------------------
// K1: blocks [0,40): fs[n] = tree_sum16(filters[n,:]) (inf-pad to NF_PAD);
//     blocks [40,104): xsum (bit-exact R7 math), 4 (b,w) groups per block.
// (VERBATIM from R10 — verified.)
// ---------------------------------------------------------------------------
__global__ __launch_bounds__(256) void prep_kernel(const float* __restrict__ x,
                                                   const float* __restrict__ filters,
                                                   float* __restrict__ fs,
                                                   float* __restrict__ xsum) {
    int bid = blockIdx.x;
    int tid = threadIdx.x;

    if (bid < FSUM_BLOCKS) {
        int n = bid * 256 + tid;
        float val;
        if (n >= NF) {
            val = __builtin_inff();
        } else {
            const float4* fp = reinterpret_cast<const float4*>(filters + n * PATCH);
            float4 v0 = fp[0], v1 = fp[1], v2 = fp[2], v3 = fp[3];
            float a[16] = {v0.x, v0.y, v0.z, v0.w, v1.x, v1.y, v1.z, v1.w,
                           v2.x, v2.y, v2.z, v2.w, v3.x, v3.y, v3.z, v3.w};
            val = tree_sum16(a);
        }
        fs[n] = val;
        return;
    }

    __shared__ float lds[4][64][17];
    __shared__ float smn[4][16], sinv[4][16];
    int grp = (bid - FSUM_BLOCKS) * 4 + (tid >> 6);   // 0..255
    int h   = tid & 63;
    int g   = tid >> 6;
    int b   = grp >> 5, w = grp & 31;
    const float4* xp = reinterpret_cast<const float4*>(
        x + (size_t)(((b * HH + h) * WW + w) * PATCH));
    float4 v0 = xp[0], v1 = xp[1], v2 = xp[2], v3 = xp[3];
    float vv[16] = {v0.x, v0.y, v0.z, v0.w, v1.x, v1.y, v1.z, v1.w,
                    v2.x, v2.y, v2.z, v2.w, v3.x, v3.y, v3.z, v3.w};
    #pragma unroll
    for (int j = 0; j < 16; ++j) lds[g][h][j] = vv[j];
    __syncthreads();
    if (h < 16) {
        float mn = lds[g][0][h], mx = mn;
        for (int i = 1; i < 64; ++i) {
            float t = lds[g][i][h];
            mn = fminf(mn, t);
            mx = fmaxf(mx, t);
        }
        smn[g][h] = mn;
        float rg = (mx - mn) + 1e-8f;         // f32, reference order
        sinv[g][h] = 1.0f / rg;               // hoisted reciprocal (R7-confirmed)
    }
    __syncthreads();
    float xs[16];
    #pragma unroll
    for (int j = 0; j < 16; ++j) xs[j] = (vv[j] - smn[g][j]) * sinv[g][j];
    xsum[(b * HH + h) * WW + w] = tree_sum16(xs);
}

// ---------------------------------------------------------------------------
// K2: single block builds the GLOBAL bucket CSR from fs (40 KB, L2-resident).
// Hist -> exclusive scan -> scatter (R10-verified code; order within bucket
// arbitrary and harmless: query comparator is exact lexicographic (d, idx)).
// ---------------------------------------------------------------------------
__global__ __launch_bounds__(256) void csr_kernel(const float* __restrict__ fs,
                                                  int* __restrict__ off,
                                                  float2* __restrict__ csr) {
    __shared__ int hist[NBUCK];
    __shared__ int cur[NBUCK];
    __shared__ int wsum[4];
    int tid = threadIdx.x;
    int lane = tid & 63, wv = tid >> 6;

    for (int i = tid; i < NBUCK; i += 256) hist[i] = 0;
    __syncthreads();

    const float4* fs4 = reinterpret_cast<const float4*>(fs);
    float4 vreg[10];
    #pragma unroll
    for (int j = 0; j < 10; ++j) vreg[j] = fs4[j * 256 + tid];
    #pragma unroll
    for (int j = 0; j < 10; ++j) {
        int n0 = (j * 256 + tid) * 4;
        float a[4] = {vreg[j].x, vreg[j].y, vreg[j].z, vreg[j].w};
        #pragma unroll
        for (int e = 0; e < 4; ++e) {
            if (n0 + e < NF) {
                int k = (int)floorf(a[e] * 100.0f + 0.5f);
                k = min(max(k, 0), NBUCK - 1);
                atomicAdd(&hist[k], 1);
            }
        }
    }
    __syncthreads();

    // exclusive scan over 1792 bins (7/thread + wave + cross-wave) — verified
    int h7[BPT];
    int b0 = tid * BPT;
    int lsum = 0;
    #pragma unroll
    for (int j = 0; j < BPT; ++j) { h7[j] = hist[b0 + j]; lsum += h7[j]; }
    int v = lsum;
    #pragma unroll
    for (int d = 1; d < 64; d <<= 1) {
        int t = __shfl_up(v, d, 64);
        if (lane >= d) v += t;
    }
    if (lane == 63) wsum[wv] = v;
    __syncthreads();
    int woff = 0;
    for (int i = 0; i < wv; ++i) woff += wsum[i];
    int run = woff + v - lsum;
    #pragma unroll
    for (int j = 0; j < BPT; ++j) {
        off[b0 + j] = run;
        cur[b0 + j] = run;
        run += h7[j];
    }
    if (tid == 255) off[NBUCK] = run;   // = NF
    __syncthreads();

    // scatter to global CSR
    #pragma unroll
    for (int j = 0; j < 10; ++j) {
        int n0 = (j * 256 + tid) * 4;
        float a[4] = {vreg[j].x, vreg[j].y, vreg[j].z, vreg[j].w};
        #pragma unroll
        for (int e = 0; e < 4; ++e) {
            if (n0 + e < NF) {
                int k = (int)floorf(a[e] * 100.0f + 0.5f);
                k = min(max(k, 0), NBUCK - 1);
                int p = atomicAdd(&cur[k], 1);
                csr[p] = make_float2(a[e], __int_as_float(n0 + e));
            }
        }
    }
}

// ---------------------------------------------------------------------------
// K3: search + gather, high occupancy (LDS ~= 128 B -> many blocks/CU).
// Threads 0..QPB-1 ring-search their query straight from L2 (R9-verified
// prune + exact lexicographic (d,idx) comparator); then all 4 waves gather
// emb rows (8 rows/wave, float2 lanes). 512 blocks x 32 queries = 16384.
// ---------------------------------------------------------------------------
__global__ __launch_bounds__(256) void search_gather_kernel(
        const int* __restrict__ off, const float2* __restrict__ csr,
        const float* __restrict__ xsum, const float* __restrict__ emb,
        float* __restrict__ out) {
    __shared__ int sidx[QPB];
    int tid = threadIdx.x;
    int lane = tid & 63, wv = tid >> 6;

    if (tid < QPB) {
        int q = blockIdx.x * QPB + tid;
        float s = xsum[q];
        int kq = (int)floorf(s * 100.0f + 0.5f);
        kq = min(max(kq, 0), NBUCK - 1);
        float bd = __builtin_inff();
        int bi = 0x7fffffff;
        for (int r = 0; r < NBUCK; ++r) {
            float bound = 0.01f * (float)r - 0.0052f;   // R9-verified prune
            if (bd < bound) break;
            #pragma unroll
            for (int side = 0; side < 2; ++side) {
                if (r == 0 && side == 1) continue;
                int k = side ? kq + r : kq - r;
                if ((unsigned)k >= NBUCK) continue;
                int p0 = off[k], p1 = off[k + 1];
                for (int p = p0; p < p1; ++p) {
                    float2 m = csr[p];
                    float d = fabsf(m.x - s);           // exact ref arithmetic
                    int mi = __float_as_int(m.y);
                    if (d < bd) { bd = d; bi = mi; }
                    else if (d == bd && mi < bi) { bi = mi; }
                }
            }
        }
        sidx[tid] = bi;
    }
    __syncthreads();

    #pragma unroll
    for (int i = 0; i < QPB / 4; ++i) {         // 8 rows per wave
        int row = i * 4 + wv;
        int bi  = sidx[row];
        int q   = blockIdx.x * QPB + row;
        const float2* er = reinterpret_cast<const float2*>(emb + (size_t)bi * ENC);
        float2*       op = reinterpret_cast<float2*>(out + (size_t)q * ENC);
        op[lane] = er[lane];
    }
}

// ---------------------------------------------------------------------------
extern "C" void kernel_launch(void* const* d_in, const int* in_sizes, int n_in,
                              void* d_out, int out_size, void* d_ws, size_t ws_size,
                              hipStream_t stream) {
    const float* x       = (const float*)d_in[0];  // (8,64,32,16)
    const float* filters = (const float*)d_in[1];  // (10000,16)
    const float* emb     = (const float*)d_in[2];  // (10000,128)
    float* out = (float*)d_out;                    // (8,64,32,128)

    // ws layout: fs f32[NF_PAD] | xsum f32[NPOS] | off int[NBUCK+1] (pad) | csr float2[NF]
    char* wsb = (char*)d_ws;
    float*  fs   = (float*)wsb;                               // 40 KB
    float*  xsum = (float*)(wsb + 40960);                     // 64 KB
    int*    off  = (int*)(wsb + 40960 + 65536);               // 7.2 KB -> pad 8 KB
    float2* csr  = (float2*)(wsb + 40960 + 65536 + 8192);     // 80 KB

    prep_kernel<<<FSUM_BLOCKS + XSUM_BLOCKS, 256, 0, stream>>>(x, filters, fs, xsum);
    csr_kernel<<<1, 256, 0, stream>>>(fs, off, csr);
    search_gather_kernel<<<NPOS / QPB, 256, 0, stream>>>(off, csr, xsum, emb, out);
}